// Round 7
// baseline (1260.394 us; speedup 1.0000x reference)
//
#include <hip/hip_runtime.h>
#include <hip/hip_fp16.h>

#define NNODES 100000
#define NEDGES 1600000
#define NGRAPH 512
#define DIM    100
#define DP     128
#define SLICES 7
#define EPSBN  1e-5f
#define NBUK   ((NNODES + 255) >> 8)
#define BINCH  2048
#define PERW   32            // nodes per wave per claim
#define NCH    128           // nodes per claim (4 waves * PERW)
#define QPAD   32            // ints between queue counters (128B)

typedef _Float16 half8 __attribute__((ext_vector_type(8)));
typedef float floatx4 __attribute__((ext_vector_type(4)));

// sliced gather buffer: T[slice][node][16 halves], node range [0, n] (row n = zeros)

// ---------------- pass 0: per-chunk bucket counts ----------------
__global__ __launch_bounds__(512) void bin_count_kernel(const int* __restrict__ dst,
                                                        int* __restrict__ btotal, int e) {
    __shared__ int lc[NBUK];
    int tid = threadIdx.x;
    int base = blockIdx.x * BINCH;
    int m = e - base; if (m > BINCH) m = BINCH;
    for (int b = tid; b < NBUK; b += 512) lc[b] = 0;
    __syncthreads();
    for (int j = tid; j < m; j += 512)
        atomicAdd(&lc[dst[base + j] >> 8], 1);
    __syncthreads();
    for (int b = tid; b < NBUK; b += 512)
        if (lc[b]) atomicAdd(&btotal[b], lc[b]);
}

// ---------------- bucket exclusive scan + graph boundaries (fused) ----------------
__global__ void bucket_scan_kernel(const int* __restrict__ btotal, int* __restrict__ bbase,
                                   int* __restrict__ bcursor, int e,
                                   const int* __restrict__ batch, int* __restrict__ gstart, int n) {
    __shared__ int s[512];
    int tid = threadIdx.x;
    int v = (tid < NBUK) ? btotal[tid] : 0;
    s[tid] = v; __syncthreads();
    for (int o = 1; o < 512; o <<= 1) {
        int t = (tid >= o) ? s[tid - o] : 0;
        __syncthreads();
        s[tid] += t;
        __syncthreads();
    }
    if (tid < NBUK) {
        int base = s[tid] - v;
        bbase[tid] = base;
        bcursor[tid] = base;
    }
    if (tid == 0) bbase[NBUK] = e;

    {
        int g = tid;
        int lo = 0, hi = n;
        while (lo < hi) {
            int mid = (lo + hi) >> 1;
            if (batch[mid] < g) lo = mid + 1; else hi = mid;
        }
        gstart[g] = lo;
        if (g == 0) gstart[NGRAPH] = n;
    }
}

// ---------------- pass 1: bin pairs bucket-major (packed output, parallel scan) ----------------
__global__ __launch_bounds__(512) void bin_kernel(
        const int* __restrict__ src, const int* __restrict__ dst,
        int* __restrict__ bcursor, unsigned int* __restrict__ gpairs, int e) {
    __shared__ int2 lpairs[BINCH];
    __shared__ int lcount[NBUK], lstart[NBUK], lcur[NBUK], gbase[NBUK];
    __shared__ int s[512];
    int tid = threadIdx.x;
    int base = blockIdx.x * BINCH;
    int m = e - base; if (m > BINCH) m = BINCH;

    for (int b = tid; b < NBUK; b += 512) lcount[b] = 0;
    __syncthreads();
    for (int j = tid; j < m; j += 512)
        atomicAdd(&lcount[dst[base + j] >> 8], 1);
    __syncthreads();

    int v = (tid < NBUK) ? lcount[tid] : 0;
    s[tid] = v; __syncthreads();
    for (int o = 1; o < 512; o <<= 1) {
        int t = (tid >= o) ? s[tid - o] : 0;
        __syncthreads();
        s[tid] += t;
        __syncthreads();
    }
    if (tid < NBUK) {
        lstart[tid] = s[tid] - v;
        lcur[tid] = s[tid] - v;
        gbase[tid] = atomicAdd(&bcursor[tid], v);
    }
    __syncthreads();

    for (int j = tid; j < m; j += 512) {
        int sv = src[base + j], d = dst[base + j];
        int p = atomicAdd(&lcur[d >> 8], 1);
        lpairs[p] = make_int2(sv, d);
    }
    __syncthreads();
    for (int j = tid; j < m; j += 512) {
        int2 pr = lpairs[j];
        int b = pr.y >> 8;
        gpairs[gbase[b] + (j - lstart[b])] =
            ((unsigned int)pr.x << 8) | ((unsigned int)pr.y & 255u);
    }
}

// ---------------- pass 2: fused per-bucket build (packed input) ----------------
__global__ __launch_bounds__(256) void bucket_build_kernel(
        const unsigned int* __restrict__ gpairs, const int* __restrict__ bbase,
        int* __restrict__ off, int* __restrict__ ssorted,
        float* __restrict__ dsl, float* __restrict__ dnsl, int n, int e) {
    __shared__ int cnt[256];
    __shared__ int sc[256];
    int b = blockIdx.x, tid = threadIdx.x;
    int node0 = b << 8;
    int e0 = bbase[b], e1 = bbase[b + 1];

    cnt[tid] = 0;
    __syncthreads();
    for (int j = e0 + tid; j < e1; j += 256)
        atomicAdd(&cnt[gpairs[j] & 255u], 1);
    __syncthreads();

    int c = cnt[tid];
    sc[tid] = c; __syncthreads();
    for (int o = 1; o < 256; o <<= 1) {
        int t = (tid >= o) ? sc[tid - o] : 0;
        __syncthreads();
        sc[tid] += t;
        __syncthreads();
    }
    int excl = sc[tid] - c;

    int node = node0 + tid;
    if (node < n) {
        off[node] = e0 + excl;
        float cf = (float)c;
        dsl[node] = rsqrtf(cf + 1.0f);
        dnsl[node] = (c > 0) ? rsqrtf(cf) : 0.0f;
    }
    if (b == NBUK - 1 && tid == 0) off[n] = e;

    __syncthreads();
    cnt[tid] = e0 + excl;
    __syncthreads();
    for (int j = e0 + tid; j < e1; j += 256) {
        unsigned int pk = gpairs[j];
        int p = atomicAdd(&cnt[pk & 255u], 1);
        ssorted[p] = (int)(pk >> 8);
    }
}

// ---------------- pack all 4 W into MFMA fragment order + aux init block ----------------
__global__ void packW4_kernel(const float* __restrict__ W1, const float* __restrict__ W2,
                              const float* __restrict__ W3, const float* __restrict__ W4,
                              _Float16* __restrict__ Wt1, _Float16* __restrict__ Wt2,
                              _Float16* __restrict__ Wt3, _Float16* __restrict__ Wt4,
                              const float* __restrict__ b1, const float* __restrict__ b2,
                              float* __restrict__ b1p, float* __restrict__ b2p,
                              int* __restrict__ btotal, float* __restrict__ bnsum,
                              float* __restrict__ bnsq, __half* __restrict__ buf0,
                              int* __restrict__ qcur, int n) {
    if (blockIdx.x == 256) {
        int t = threadIdx.x;
        if (t < 128) {
            b1p[t] = (t < DIM) ? b1[t] : 0.f;
            b2p[t] = (t < DIM) ? b2[t] : 0.f;
            bnsum[t] = 0.f;
            bnsq[t] = 0.f;
        }
        for (int i = t; i < NBUK; i += 256) btotal[i] = 0;
        for (int i = t; i < 3 * SLICES * QPAD; i += 256) qcur[i] = 0;
        // zero rows: row n of each slice (7 x 32B)
        if (t < SLICES * 8) {
            int sl = t >> 3, wd = t & 7;
            ((unsigned int*)buf0)[((size_t)sl * (n + 1) + n) * 8 + wd] = 0u;
        }
        return;
    }
    int which = blockIdx.x >> 6;          // 64 blocks per weight
    int idx = (blockIdx.x & 63) * 256 + threadIdx.x;
    const float* W = (which == 0) ? W1 : (which == 1) ? W2 : (which == 2) ? W3 : W4;
    _Float16* Wt  = (which == 0) ? Wt1 : (which == 1) ? Wt2 : (which == 2) ? Wt3 : Wt4;
    int K = (which == 0) ? 128 : DIM;
    int j = idx & 7;
    int l = (idx >> 3) & 63;
    int c = idx >> 9;
    int t = c >> 2, k0 = c & 3;
    int nn = t * 16 + (l & 15);
    int k = k0 * 32 + (l >> 4) * 8 + j;
    float v = (k < K && nn < DIM) ? W[k * DIM + nn] : 0.f;
    Wt[idx] = (_Float16)v;
}

// ---------------- sliced propagation (persistent, XCD-affine work queue) ----------------
// bias != nullptr : out = relu(dinv*(sum+self) + bias)   [self-loop variant]
// bias == nullptr : out = relu(dinv*sum + R[v])          [ARMA variant]
// T sliced [7][n+1][16]; outH / R row-major [n][128].
__global__ __launch_bounds__(256) void prop_slice_kernel(
        const __half* __restrict__ T, const int* __restrict__ ssorted,
        const int* __restrict__ off, const float* __restrict__ dinv,
        const float* __restrict__ bias, const __half* __restrict__ R,
        __half* __restrict__ outH, int* __restrict__ qcur, int n, int nchunks) {
    __shared__ int sh_sc;
    int tid = threadIdx.x;
    int lane = tid & 63;
    int w = tid >> 6;
    int half = lane >> 5;
    int p2 = lane & 31;
    const int ZR = n;

    int s0;
    {
        unsigned xcc = __builtin_amdgcn_s_getreg(0xF814) & 15u;  // HW_REG_XCC_ID
        s0 = (int)(xcc & 7u); if (s0 > 6) s0 = 6;
    }

    while (true) {
        if (tid == 0) {
            int got = -1;
            int c = atomicAdd(&qcur[s0 * QPAD], 1);
            if (c < nchunks) got = (s0 << 16) | c;
            else {
                for (int t = 1; t <= 6 && got < 0; t++) {
                    int ss = s0 + t; if (ss > 6) ss -= 7;
                    int cc = atomicAdd(&qcur[ss * QPAD], 1);
                    if (cc < nchunks) got = (ss << 16) | cc;
                }
            }
            sh_sc = got;
        }
        __syncthreads();
        int enc = sh_sc;
        __syncthreads();
        if (enc < 0) return;
        int s = enc >> 16;
        int chunk = enc & 0xFFFF;
        const __half* Ts = T + (size_t)s * (n + 1) * 16;
        int nb = chunk * NCH + w * PERW;

        for (int i = 0; i < PERW; i += 2) {
            int va = nb + i, vb = nb + i + 1;
            if (va >= n) break;
            bool haveB = (vb < n);
            int e0a = off[va], e1a = off[va + 1];
            int e0b = haveB ? off[vb] : 0, e1b = haveB ? off[vb + 1] : 0;
            int e0h = half ? e0b : e0a;
            int degh = half ? (e1b - e0b) : (e1a - e0a);

            float fa[16];
#pragma unroll
            for (int j2 = 0; j2 < 16; j2++) fa[j2] = 0.f;

            for (int base = 0; base < degh; base += 32) {
                int sidx = (base + p2 < degh) ?
                    __builtin_nontemporal_load(&ssorted[e0h + base + p2]) : ZR;
                const uint4* p = (const uint4*)&Ts[(size_t)sidx * 16];
                uint4 u0 = p[0];
                uint4 u1 = p[1];
                float2 f;
                f = __half22float2(*(__half2*)&u0.x); fa[0] += f.x;  fa[1] += f.y;
                f = __half22float2(*(__half2*)&u0.y); fa[2] += f.x;  fa[3] += f.y;
                f = __half22float2(*(__half2*)&u0.z); fa[4] += f.x;  fa[5] += f.y;
                f = __half22float2(*(__half2*)&u0.w); fa[6] += f.x;  fa[7] += f.y;
                f = __half22float2(*(__half2*)&u1.x); fa[8] += f.x;  fa[9] += f.y;
                f = __half22float2(*(__half2*)&u1.y); fa[10] += f.x; fa[11] += f.y;
                f = __half22float2(*(__half2*)&u1.z); fa[12] += f.x; fa[13] += f.y;
                f = __half22float2(*(__half2*)&u1.w); fa[14] += f.x; fa[15] += f.y;
            }

#pragma unroll
            for (int j2 = 0; j2 < 16; j2++) {
                fa[j2] += __shfl_xor(fa[j2], 1);
                fa[j2] += __shfl_xor(fa[j2], 2);
                fa[j2] += __shfl_xor(fa[j2], 4);
                fa[j2] += __shfl_xor(fa[j2], 8);
                fa[j2] += __shfl_xor(fa[j2], 16);
            }

            int v = half ? vb : va;
            bool act = (p2 < 2) && (half == 0 || haveB);
            if (act) {
                // select 8 sums with literal indices (avoid runtime-indexed spill)
                float v0 = p2 ? fa[8]  : fa[0];
                float v1 = p2 ? fa[9]  : fa[1];
                float v2 = p2 ? fa[10] : fa[2];
                float v3 = p2 ? fa[11] : fa[3];
                float v4 = p2 ? fa[12] : fa[4];
                float v5 = p2 ? fa[13] : fa[5];
                float v6 = p2 ? fa[14] : fa[6];
                float v7 = p2 ? fa[15] : fa[7];
                float dn = dinv[v];
                float o[8];
                if (bias) {
                    const uint4* sp = (const uint4*)&Ts[(size_t)v * 16];
                    uint4 su = sp[p2];
                    float2 f;
                    float sf0, sf1, sf2, sf3, sf4, sf5, sf6, sf7;
                    f = __half22float2(*(__half2*)&su.x); sf0 = f.x; sf1 = f.y;
                    f = __half22float2(*(__half2*)&su.y); sf2 = f.x; sf3 = f.y;
                    f = __half22float2(*(__half2*)&su.z); sf4 = f.x; sf5 = f.y;
                    f = __half22float2(*(__half2*)&su.w); sf6 = f.x; sf7 = f.y;
                    float4 bA = *(const float4*)&bias[s * 16 + p2 * 8];
                    float4 bB = *(const float4*)&bias[s * 16 + p2 * 8 + 4];
                    o[0] = fmaxf(dn * (v0 + sf0) + bA.x, 0.f);
                    o[1] = fmaxf(dn * (v1 + sf1) + bA.y, 0.f);
                    o[2] = fmaxf(dn * (v2 + sf2) + bA.z, 0.f);
                    o[3] = fmaxf(dn * (v3 + sf3) + bA.w, 0.f);
                    o[4] = fmaxf(dn * (v4 + sf4) + bB.x, 0.f);
                    o[5] = fmaxf(dn * (v5 + sf5) + bB.y, 0.f);
                    o[6] = fmaxf(dn * (v6 + sf6) + bB.z, 0.f);
                    o[7] = fmaxf(dn * (v7 + sf7) + bB.w, 0.f);
                } else {
                    uint4 ru = *(const uint4*)&R[(size_t)v * DP + s * 16 + p2 * 8];
                    float2 f;
                    float rf0, rf1, rf2, rf3, rf4, rf5, rf6, rf7;
                    f = __half22float2(*(__half2*)&ru.x); rf0 = f.x; rf1 = f.y;
                    f = __half22float2(*(__half2*)&ru.y); rf2 = f.x; rf3 = f.y;
                    f = __half22float2(*(__half2*)&ru.z); rf4 = f.x; rf5 = f.y;
                    f = __half22float2(*(__half2*)&ru.w); rf6 = f.x; rf7 = f.y;
                    o[0] = fmaxf(dn * v0 + rf0, 0.f);
                    o[1] = fmaxf(dn * v1 + rf1, 0.f);
                    o[2] = fmaxf(dn * v2 + rf2, 0.f);
                    o[3] = fmaxf(dn * v3 + rf3, 0.f);
                    o[4] = fmaxf(dn * v4 + rf4, 0.f);
                    o[5] = fmaxf(dn * v5 + rf5, 0.f);
                    o[6] = fmaxf(dn * v6 + rf6, 0.f);
                    o[7] = fmaxf(dn * v7 + rf7, 0.f);
                }
                __half2 q0 = __floats2half2_rn(o[0], o[1]);
                __half2 q1 = __floats2half2_rn(o[2], o[3]);
                __half2 q2 = __floats2half2_rn(o[4], o[5]);
                __half2 q3 = __floats2half2_rn(o[6], o[7]);
                uint4 u;
                u.x = *(unsigned int*)&q0;
                u.y = *(unsigned int*)&q1;
                u.z = *(unsigned int*)&q2;
                u.w = *(unsigned int*)&q3;
                *(uint4*)&outH[(size_t)v * DP + s * 16 + p2 * 8] = u;
            }
        }
    }
}

// ---------------- MFMA matmul, fp32 A (x input), 128 rows/block -> fp16 SLICED buf0 ----------------
__global__ __launch_bounds__(256) void matmul_a32_kernel(
        const float* __restrict__ A, const _Float16* __restrict__ WtF,
        const float* __restrict__ rowscale, __half* __restrict__ Ch, int M) {
    __shared__ char smraw[64 * 132 * 4];
    _Float16* Bs = (_Float16*)smraw;
    float* Ct = (float*)smraw;
    int tid = threadIdx.x;
    int wave = tid >> 6;
    int lane = tid & 63;
    int m16 = lane & 15;
    int quad = lane >> 4;
    long row0blk = (long)blockIdx.x * 128;

    {
        const uint4* s = (const uint4*)WtF;
        uint4* d = (uint4*)Bs;
        for (int i = tid; i < 2048; i += 256) d[i] = s[i];
    }

    half8 af[2][4];
#pragma unroll
    for (int t = 0; t < 2; t++) {
        long ar = row0blk + t * 64 + wave * 16 + m16; if (ar >= M) ar = M - 1;
        const float* Ap = &A[ar * DP + quad * 8];
#pragma unroll
        for (int k0 = 0; k0 < 4; k0++) {
            float4 v0 = *(const float4*)(Ap + k0 * 32);
            float4 v1 = *(const float4*)(Ap + k0 * 32 + 4);
            half8 o;
            o[0] = (_Float16)v0.x; o[1] = (_Float16)v0.y;
            o[2] = (_Float16)v0.z; o[3] = (_Float16)v0.w;
            o[4] = (_Float16)v1.x; o[5] = (_Float16)v1.y;
            o[6] = (_Float16)v1.z; o[7] = (_Float16)v1.w;
            af[t][k0] = o;
        }
    }
    __syncthreads();

    floatx4 acc[2][8];
#pragma unroll
    for (int t = 0; t < 2; t++)
#pragma unroll
        for (int a = 0; a < 8; a++) acc[t][a] = (floatx4){0.f, 0.f, 0.f, 0.f};

#pragma unroll
    for (int c = 0; c < 32; c++) {
        half8 bf = *(const half8*)&Bs[(c * 64 + lane) * 8];
        acc[0][c >> 2] = __builtin_amdgcn_mfma_f32_16x16x32_f16(af[0][c & 3], bf, acc[0][c >> 2], 0, 0, 0);
        acc[1][c >> 2] = __builtin_amdgcn_mfma_f32_16x16x32_f16(af[1][c & 3], bf, acc[1][c >> 2], 0, 0, 0);
    }

    int lrow0 = wave * 16 + quad * 4;
#pragma unroll
    for (int t = 0; t < 2; t++) {
        __syncthreads();
#pragma unroll
        for (int a = 0; a < 8; a++)
#pragma unroll
            for (int r = 0; r < 4; r++)
                Ct[(lrow0 + r) * 132 + a * 16 + m16] = acc[t][a][r];
        __syncthreads();
        for (int idx = tid; idx < 64 * 32; idx += 256) {
            int lr = idx >> 5, c4 = idx & 31;
            long grow = row0blk + t * 64 + lr;
            int col = c4 * 4;
            if (grow >= M || col >= SLICES * 16) continue;
            float4 v = *(const float4*)&Ct[lr * 132 + col];
            float rs = rowscale[grow];
            v.x *= rs; v.y *= rs; v.z *= rs; v.w *= rs;
            __half2 p01 = __floats2half2_rn(v.x, v.y);
            __half2 p23 = __floats2half2_rn(v.z, v.w);
            uint2 u;
            u.x = *(unsigned int*)&p01;
            u.y = *(unsigned int*)&p23;
            *(uint2*)&Ch[((size_t)(col >> 4) * (M + 1) + grow) * 16 + (col & 15)] = u;
        }
    }
}

// ---------------- MFMA matmul, fp16 A (row-major DP), 128 rows/block -> fp16 SLICED buf0 ----------------
__global__ __launch_bounds__(256) void matmul_a16_kernel(
        const __half* __restrict__ A, const _Float16* __restrict__ WtF,
        const float* __restrict__ rowscale, __half* __restrict__ Ch, int M) {
    __shared__ char smraw[64 * 132 * 4];
    _Float16* Bs = (_Float16*)smraw;
    float* Ct = (float*)smraw;
    int tid = threadIdx.x;
    int wave = tid >> 6;
    int lane = tid & 63;
    int m16 = lane & 15;
    int quad = lane >> 4;
    long row0blk = (long)blockIdx.x * 128;

    {
        const uint4* s = (const uint4*)WtF;
        uint4* d = (uint4*)Bs;
        for (int i = tid; i < 2048; i += 256) d[i] = s[i];
    }

    half8 af[2][4];
#pragma unroll
    for (int t = 0; t < 2; t++) {
        long ar = row0blk + t * 64 + wave * 16 + m16; if (ar >= M) ar = M - 1;
        const _Float16* Ap = (const _Float16*)&A[ar * DP + quad * 8];
#pragma unroll
        for (int k0 = 0; k0 < 4; k0++)
            af[t][k0] = *(const half8*)(Ap + k0 * 32);
    }
    __syncthreads();

    floatx4 acc[2][8];
#pragma unroll
    for (int t = 0; t < 2; t++)
#pragma unroll
        for (int a = 0; a < 8; a++) acc[t][a] = (floatx4){0.f, 0.f, 0.f, 0.f};

#pragma unroll
    for (int c = 0; c < 32; c++) {
        half8 bf = *(const half8*)&Bs[(c * 64 + lane) * 8];
        acc[0][c >> 2] = __builtin_amdgcn_mfma_f32_16x16x32_f16(af[0][c & 3], bf, acc[0][c >> 2], 0, 0, 0);
        acc[1][c >> 2] = __builtin_amdgcn_mfma_f32_16x16x32_f16(af[1][c & 3], bf, acc[1][c >> 2], 0, 0, 0);
    }

    int lrow0 = wave * 16 + quad * 4;
#pragma unroll
    for (int t = 0; t < 2; t++) {
        __syncthreads();
#pragma unroll
        for (int a = 0; a < 8; a++)
#pragma unroll
            for (int r = 0; r < 4; r++)
                Ct[(lrow0 + r) * 132 + a * 16 + m16] = acc[t][a][r];
        __syncthreads();
        for (int idx = tid; idx < 64 * 32; idx += 256) {
            int lr = idx >> 5, c4 = idx & 31;
            long grow = row0blk + t * 64 + lr;
            int col = c4 * 4;
            if (grow >= M || col >= SLICES * 16) continue;
            float4 v = *(const float4*)&Ct[lr * 132 + col];
            float rs = rowscale[grow];
            v.x *= rs; v.y *= rs; v.z *= rs; v.w *= rs;
            __half2 p01 = __floats2half2_rn(v.x, v.y);
            __half2 p23 = __floats2half2_rn(v.z, v.w);
            uint2 u;
            u.x = *(unsigned int*)&p01;
            u.y = *(unsigned int*)&p23;
            *(uint2*)&Ch[((size_t)(col >> 4) * (M + 1) + grow) * 16 + (col & 15)] = u;
        }
    }
}

// ---------------- dual MFMA matmul with fused BN: P1 -> SLICED buf0 ; R -> row-major ----------------
__global__ __launch_bounds__(256) void matmul_dual_kernel(
        const __half* __restrict__ A, const _Float16* __restrict__ WtF3,
        const _Float16* __restrict__ WtF4, const float* __restrict__ ba,
        const float* __restrict__ rowscale,
        const float* __restrict__ bnscale, const float* __restrict__ bnshift,
        __half* __restrict__ Ch1, __half* __restrict__ ChR, int M, int Kout) {
    __shared__ char smraw[64 * 132 * 4];
    _Float16* Bs = (_Float16*)smraw;
    float* Ct = (float*)smraw;
    int tid = threadIdx.x;
    int wave = tid >> 6;
    int lane = tid & 63;
    int m16 = lane & 15;
    int quad = lane >> 4;
    long row0blk = (long)blockIdx.x * 64;
    long row0 = row0blk + wave * 16;

    half8 af[4];
    {
        long ar = row0 + m16; if (ar >= M) ar = M - 1;
        const _Float16* Ap = (const _Float16*)&A[ar * DP + quad * 8];
#pragma unroll
        for (int k0 = 0; k0 < 4; k0++) {
            half8 h = *(const half8*)(Ap + k0 * 32);
            int c0 = quad * 8 + k0 * 32;
            float4 sc0 = *(const float4*)&bnscale[c0];
            float4 sc1 = *(const float4*)&bnscale[c0 + 4];
            float4 sh0 = *(const float4*)&bnshift[c0];
            float4 sh1 = *(const float4*)&bnshift[c0 + 4];
            half8 o;
            o[0] = (_Float16)((float)h[0] * sc0.x + sh0.x);
            o[1] = (_Float16)((float)h[1] * sc0.y + sh0.y);
            o[2] = (_Float16)((float)h[2] * sc0.z + sh0.z);
            o[3] = (_Float16)((float)h[3] * sc0.w + sh0.w);
            o[4] = (_Float16)((float)h[4] * sc1.x + sh1.x);
            o[5] = (_Float16)((float)h[5] * sc1.y + sh1.y);
            o[6] = (_Float16)((float)h[6] * sc1.z + sh1.z);
            o[7] = (_Float16)((float)h[7] * sc1.w + sh1.w);
            af[k0] = o;
        }
    }

    floatx4 acc3[8], acc4[8];
#pragma unroll
    for (int t = 0; t < 8; t++) {
        acc3[t] = (floatx4){0.f, 0.f, 0.f, 0.f};
        acc4[t] = (floatx4){0.f, 0.f, 0.f, 0.f};
    }

    {
        const uint4* s = (const uint4*)WtF3;
        uint4* d = (uint4*)Bs;
        for (int i = tid; i < 2048; i += 256) d[i] = s[i];
    }
    __syncthreads();
#pragma unroll
    for (int c = 0; c < 32; c++) {
        half8 bf = *(const half8*)&Bs[(c * 64 + lane) * 8];
        acc3[c >> 2] = __builtin_amdgcn_mfma_f32_16x16x32_f16(af[c & 3], bf, acc3[c >> 2], 0, 0, 0);
    }
    __syncthreads();

    {
        const uint4* s = (const uint4*)WtF4;
        uint4* d = (uint4*)Bs;
        for (int i = tid; i < 2048; i += 256) d[i] = s[i];
    }
    __syncthreads();
#pragma unroll
    for (int c = 0; c < 32; c++) {
        half8 bf = *(const half8*)&Bs[(c * 64 + lane) * 8];
        acc4[c >> 2] = __builtin_amdgcn_mfma_f32_16x16x32_f16(af[c & 3], bf, acc4[c >> 2], 0, 0, 0);
    }
    __syncthreads();

    int lrow0 = wave * 16 + quad * 4;

    // --- P1 epilogue: rowscale, sliced store ---
#pragma unroll
    for (int t = 0; t < 8; t++)
#pragma unroll
        for (int r = 0; r < 4; r++)
            Ct[(lrow0 + r) * 132 + t * 16 + m16] = acc3[t][r];
    __syncthreads();
    for (int idx = tid; idx < 64 * 32; idx += 256) {
        int lr = idx >> 5, c4 = idx & 31;
        long grow = row0blk + lr;
        int col = c4 * 4;
        if (grow >= M || col >= SLICES * 16) continue;
        float4 v = *(const float4*)&Ct[lr * 132 + col];
        float rs = rowscale[grow];
        v.x *= rs; v.y *= rs; v.z *= rs; v.w *= rs;
        __half2 p01 = __floats2half2_rn(v.x, v.y);
        __half2 p23 = __floats2half2_rn(v.z, v.w);
        uint2 u;
        u.x = *(unsigned int*)&p01;
        u.y = *(unsigned int*)&p23;
        *(uint2*)&Ch1[((size_t)(col >> 4) * (M + 1) + grow) * 16 + (col & 15)] = u;
    }
    __syncthreads();

    // --- R epilogue: +ba, row-major store ---
#pragma unroll
    for (int t = 0; t < 8; t++)
#pragma unroll
        for (int r = 0; r < 4; r++)
            Ct[(lrow0 + r) * 132 + t * 16 + m16] = acc4[t][r];
    __syncthreads();
    for (int idx = tid; idx < 64 * 32; idx += 256) {
        int lr = idx >> 5, c4 = idx & 31;
        long grow = row0blk + lr;
        if (grow >= M) continue;
        int col = c4 * 4;
        float4 v = *(const float4*)&Ct[lr * 132 + col];
        if (col + 4 <= Kout) {
            float4 bb = *(const float4*)&ba[col];
            v.x += bb.x; v.y += bb.y; v.z += bb.z; v.w += bb.w;
        }
        __half2 p01 = __floats2half2_rn(v.x, v.y);
        __half2 p23 = __floats2half2_rn(v.z, v.w);
        uint2 u;
        u.x = *(unsigned int*)&p01;
        u.y = *(unsigned int*)&p23;
        *(uint2*)&ChR[grow * DP + col] = u;
    }
}

// ---------------- BN stats over h2 (row-major DP) ----------------
__global__ __launch_bounds__(512) void bnstats_kernel(const __half* __restrict__ h,
                                                      float* __restrict__ bnsum,
                                                      float* __restrict__ bnsq, int n) {
    __shared__ float2 sred[512], qred[512];
    int tid = threadIdx.x;
    int col2 = tid & 63;
    int rgrp = tid >> 6;
    float2 s = make_float2(0.f, 0.f), qv = make_float2(0.f, 0.f);
    if (col2 < 52) {
        for (int r = blockIdx.x * 8 + rgrp; r < n; r += gridDim.x * 8) {
            __half2 hv = *(const __half2*)&h[(long)r * DP + col2 * 2];
            float2 f = __half22float2(hv);
            s.x += f.x; s.y += f.y;
            qv.x += f.x * f.x; qv.y += f.y * f.y;
        }
    }
    sred[tid] = s; qred[tid] = qv;
    __syncthreads();
    if (tid < 52) {
        float2 ts = make_float2(0.f, 0.f), tq = make_float2(0.f, 0.f);
#pragma unroll
        for (int gg = 0; gg < 8; gg++) {
            float2 v = sred[gg * 64 + tid]; ts.x += v.x; ts.y += v.y;
            v = qred[gg * 64 + tid]; tq.x += v.x; tq.y += v.y;
        }
        atomicAdd(&bnsum[tid * 2], ts.x);
        atomicAdd(&bnsum[tid * 2 + 1], ts.y);
        atomicAdd(&bnsq[tid * 2], tq.x);
        atomicAdd(&bnsq[tid * 2 + 1], tq.y);
    }
}

// ---------------- bn prep ----------------
__global__ void bn_prep_kernel(const float* __restrict__ sum, const float* __restrict__ sq,
                               const float* __restrict__ gamma, const float* __restrict__ beta,
                               float* __restrict__ scale, float* __restrict__ shift, int n) {
    int c = threadIdx.x;
    float sc = 0.f, sh = 0.f;
    if (c < DIM) {
        float inv_n = 1.0f / (float)n;
        float mu = sum[c] * inv_n;
        float var = sq[c] * inv_n - mu * mu;
        float rs = rsqrtf(var + EPSBN);
        sc = rs * gamma[c];
        sh = beta[c] - mu * sc;
    }
    scale[c] = sc;
    shift[c] = sh;
}

// ---------------- fused global add pool + MLP head (row-major input) ----------------
__global__ __launch_bounds__(512) void pmlp_kernel(
        const __half* __restrict__ a, const int* __restrict__ gstart,
        const float* __restrict__ Wf1, const float* __restrict__ bf1,
        const float* __restrict__ Wf2, const float* __restrict__ bf2,
        const float* __restrict__ Wf3, const float* __restrict__ bf3,
        const float* __restrict__ Wf4, const float* __restrict__ bf4,
        float* __restrict__ out) {
    __shared__ float2 red[512];
    __shared__ float gsum[128], a1[200], a2[300], a3[200], red1[512];
    int b = blockIdx.x, tid = threadIdx.x;

    {
        int col2 = tid & 63;
        int rgrp = tid >> 6;
        int lo = gstart[b], hi = gstart[b + 1];
        float2 s = make_float2(0.f, 0.f);
        for (int r = lo + rgrp; r < hi; r += 8) {
            __half2 h = *(const __half2*)&a[(long)r * DP + col2 * 2];
            float2 f = __half22float2(h);
            s.x += f.x; s.y += f.y;
        }
        red[tid] = s;
        __syncthreads();
        if (tid < 64) {
            float2 t = make_float2(0.f, 0.f);
#pragma unroll
            for (int gg = 0; gg < 8; gg++) {
                float2 v = red[gg * 64 + tid];
                t.x += v.x; t.y += v.y;
            }
            gsum[tid * 2] = t.x;
            gsum[tid * 2 + 1] = t.y;
        }
        __syncthreads();
    }

    for (int c = tid; c < 200; c += 512) {
        float s = bf1[c];
        for (int k = 0; k < 100; k++) s += gsum[k] * Wf1[k * 200 + c];
        a1[c] = fmaxf(s, 0.f);
    }
    __syncthreads();
    for (int c = tid; c < 300; c += 512) {
        float s = bf2[c];
        for (int k = 0; k < 200; k++) s += a1[k] * Wf2[k * 300 + c];
        a2[c] = fmaxf(s, 0.f);
    }
    __syncthreads();
    for (int c = tid; c < 200; c += 512) {
        float s = bf3[c];
        for (int k = 0; k < 300; k++) s += a2[k] * Wf3[k * 200 + c];
        a3[c] = fmaxf(s, 0.f);
    }
    __syncthreads();
    red1[tid] = (tid < 200) ? a3[tid] * Wf4[tid] : 0.f;
    __syncthreads();
    for (int o = 256; o > 0; o >>= 1) {
        if (tid < o) red1[tid] += red1[tid + o];
        __syncthreads();
    }
    if (tid == 0) out[b] = red1[0] + bf4[0];
}

extern "C" void kernel_launch(void* const* d_in, const int* in_sizes, int n_in,
                              void* d_out, int out_size, void* d_ws, size_t ws_size,
                              hipStream_t stream) {
    const float* x      = (const float*)d_in[0];
    const int*   src    = (const int*)d_in[1];
    const int*   dst    = (const int*)d_in[2];
    const int*   batch  = (const int*)d_in[3];
    const float* W1     = (const float*)d_in[4];
    const float* b1     = (const float*)d_in[5];
    const float* W2     = (const float*)d_in[6];
    const float* b2     = (const float*)d_in[7];
    const float* gamma  = (const float*)d_in[8];
    const float* beta   = (const float*)d_in[9];
    const float* Wa_init= (const float*)d_in[10];
    const float* Wa_root= (const float*)d_in[11];
    const float* ba     = (const float*)d_in[12];
    const float* Wf1    = (const float*)d_in[13];
    const float* bf1    = (const float*)d_in[14];
    const float* Wf2    = (const float*)d_in[15];
    const float* bf2    = (const float*)d_in[16];
    const float* Wf3    = (const float*)d_in[17];
    const float* bf3    = (const float*)d_in[18];
    const float* Wf4    = (const float*)d_in[19];
    const float* bf4    = (const float*)d_in[20];
    float* out = (float*)d_out;

    const int n = NNODES;
    const int e = NEDGES;

    char* ws = (char*)d_ws;
    auto carve = [&](size_t bytes) -> void* {
        void* p = (void*)ws;
        ws += (bytes + 255) & ~(size_t)255;
        return p;
    };
    __half* buf0    = (__half*)carve((size_t)SLICES * (n + 1) * 16 * 2); // sliced gather src (+zero rows)
    __half* buf1    = (__half*)carve((size_t)n * DP * 2);                // H1 / H2 (row-major)
    __half* bufR    = (__half*)carve((size_t)n * DP * 2);                // R (row-major)
    __half* bufC    = (__half*)carve((size_t)n * DP * 2);                // ARMA out (row-major)
    _Float16* Wt1   = (_Float16*)carve((size_t)DP * DP * 2);
    _Float16* Wt2   = (_Float16*)carve((size_t)DP * DP * 2);
    _Float16* Wt3   = (_Float16*)carve((size_t)DP * DP * 2);
    _Float16* Wt4   = (_Float16*)carve((size_t)DP * DP * 2);
    int*    off     = (int*)carve((size_t)(n + 1) * 4);
    int*    btotal  = (int*)carve((size_t)NBUK * 4);
    int*    bbase   = (int*)carve((size_t)(NBUK + 1) * 4);
    int*    bcursor = (int*)carve((size_t)NBUK * 4);
    int*    ssorted = (int*)carve((size_t)e * 4);
    unsigned int* gpairs = (unsigned int*)carve((size_t)e * 4);
    float*  dinv_sl = (float*)carve((size_t)n * 4);
    float*  dinv_nsl= (float*)carve((size_t)n * 4);
    float*  bnsum   = (float*)carve(DP * 4);
    float*  bnsq    = (float*)carve(DP * 4);
    float*  bnscale = (float*)carve(DP * 4);
    float*  bnshift = (float*)carve(DP * 4);
    float*  b1p     = (float*)carve(DP * 4);
    float*  b2p     = (float*)carve(DP * 4);
    int*    qcur    = (int*)carve((size_t)3 * SLICES * QPAD * 4);
    int*    gstart  = (int*)carve((size_t)(NGRAPH + 1) * 4);

    const int nchunk = (e + BINCH - 1) / BINCH;
    const int nchunks = (n + NCH - 1) / NCH;      // prop chunks per slice
    const int prop_grid = 2048;                   // persistent blocks (8/CU)

    // ---- pack weights + aux init (biases, counters, queues, zero rows) ----
    packW4_kernel<<<257, 256, 0, stream>>>(W1, W2, Wa_init, Wa_root, Wt1, Wt2, Wt3, Wt4,
                                           b1, b2, b1p, b2p, btotal, bnsum, bnsq,
                                           buf0, qcur, n);

    // ---- build CSR by dst ----
    bin_count_kernel<<<nchunk, 512, 0, stream>>>(dst, btotal, e);
    bucket_scan_kernel<<<1, 512, 0, stream>>>(btotal, bbase, bcursor, e, batch, gstart, n);
    bin_kernel<<<nchunk, 512, 0, stream>>>(src, dst, bcursor, gpairs, e);
    bucket_build_kernel<<<NBUK, 256, 0, stream>>>(gpairs, bbase, off, ssorted, dinv_sl, dinv_nsl, n, e);

    const int mm_blocks128 = (n + 127) / 128;
    const int mm_blocks64 = (n + 63) / 64;

    // ---- SGConv 1 (matmul first: prop(x)@W1 == prop(x@W1)) ----
    matmul_a32_kernel<<<mm_blocks128, 256, 0, stream>>>(x, Wt1, dinv_sl, buf0, n);
    prop_slice_kernel<<<prop_grid, 256, 0, stream>>>(buf0, ssorted, off, dinv_sl, b1p, nullptr, buf1, qcur, n, nchunks);

    // ---- SGConv 2 ----
    matmul_a16_kernel<<<mm_blocks128, 256, 0, stream>>>(buf1, Wt2, dinv_sl, buf0, n);
    prop_slice_kernel<<<prop_grid, 256, 0, stream>>>(buf0, ssorted, off, dinv_sl, b2p, nullptr, buf1, qcur + SLICES * QPAD, n, nchunks);

    // ---- BatchNorm stats + params ----
    bnstats_kernel<<<512, 512, 0, stream>>>(buf1, bnsum, bnsq, n);
    bn_prep_kernel<<<1, 128, 0, stream>>>(bnsum, bnsq, gamma, beta, bnscale, bnshift, n);

    // ---- ARMAConv: dual matmul with fused BN, then sliced prop with fused add+relu ----
    matmul_dual_kernel<<<mm_blocks64, 256, 0, stream>>>(buf1, Wt3, Wt4, ba, dinv_nsl, bnscale, bnshift, buf0, bufR, n, DIM);
    prop_slice_kernel<<<prop_grid, 256, 0, stream>>>(buf0, ssorted, off, dinv_nsl, nullptr, bufR, bufC, qcur + 2 * SLICES * QPAD, n, nchunks);

    // ---- fused global add pool + MLP head ----
    pmlp_kernel<<<NGRAPH, 512, 0, stream>>>(bufC, gstart, Wf1, bf1, Wf2, bf2, Wf3, bf3, Wf4, bf4, out);
}

// Round 8
// 499.058 us; speedup vs baseline: 2.5255x; 2.5255x over previous
//
#include <hip/hip_runtime.h>
#include <hip/hip_fp16.h>

#define NNODES 100000
#define NEDGES 1600000
#define NGRAPH 512
#define DIM    100
#define DP     128
#define EPSBN  1e-5f
#define NBUK   ((NNODES + 255) >> 8)
#define BINCH  2048

typedef _Float16 half8 __attribute__((ext_vector_type(8)));
typedef float floatx4 __attribute__((ext_vector_type(4)));

// ---------------- pass 0: per-chunk bucket counts ----------------
__global__ __launch_bounds__(512) void bin_count_kernel(const int* __restrict__ dst,
                                                        int* __restrict__ btotal, int e) {
    __shared__ int lc[NBUK];
    int tid = threadIdx.x;
    int base = blockIdx.x * BINCH;
    int m = e - base; if (m > BINCH) m = BINCH;
    for (int b = tid; b < NBUK; b += 512) lc[b] = 0;
    __syncthreads();
    for (int j = tid; j < m; j += 512)
        atomicAdd(&lc[dst[base + j] >> 8], 1);
    __syncthreads();
    for (int b = tid; b < NBUK; b += 512)
        if (lc[b]) atomicAdd(&btotal[b], lc[b]);
}

// ---------------- bucket exclusive scan + graph boundaries (fused) ----------------
__global__ void bucket_scan_kernel(const int* __restrict__ btotal, int* __restrict__ bbase,
                                   int* __restrict__ bcursor, int e,
                                   const int* __restrict__ batch, int* __restrict__ gstart, int n) {
    __shared__ int s[512];
    int tid = threadIdx.x;
    int v = (tid < NBUK) ? btotal[tid] : 0;
    s[tid] = v; __syncthreads();
    for (int o = 1; o < 512; o <<= 1) {
        int t = (tid >= o) ? s[tid - o] : 0;
        __syncthreads();
        s[tid] += t;
        __syncthreads();
    }
    if (tid < NBUK) {
        int base = s[tid] - v;
        bbase[tid] = base;
        bcursor[tid] = base;
    }
    if (tid == 0) bbase[NBUK] = e;

    {
        int g = tid;
        int lo = 0, hi = n;
        while (lo < hi) {
            int mid = (lo + hi) >> 1;
            if (batch[mid] < g) lo = mid + 1; else hi = mid;
        }
        gstart[g] = lo;
        if (g == 0) gstart[NGRAPH] = n;
    }
}

// ---------------- pass 1: bin pairs bucket-major (packed output, parallel scan) ----------------
__global__ __launch_bounds__(512) void bin_kernel(
        const int* __restrict__ src, const int* __restrict__ dst,
        int* __restrict__ bcursor, unsigned int* __restrict__ gpairs, int e) {
    __shared__ int2 lpairs[BINCH];
    __shared__ int lcount[NBUK], lstart[NBUK], lcur[NBUK], gbase[NBUK];
    __shared__ int s[512];
    int tid = threadIdx.x;
    int base = blockIdx.x * BINCH;
    int m = e - base; if (m > BINCH) m = BINCH;

    for (int b = tid; b < NBUK; b += 512) lcount[b] = 0;
    __syncthreads();
    for (int j = tid; j < m; j += 512)
        atomicAdd(&lcount[dst[base + j] >> 8], 1);
    __syncthreads();

    int v = (tid < NBUK) ? lcount[tid] : 0;
    s[tid] = v; __syncthreads();
    for (int o = 1; o < 512; o <<= 1) {
        int t = (tid >= o) ? s[tid - o] : 0;
        __syncthreads();
        s[tid] += t;
        __syncthreads();
    }
    if (tid < NBUK) {
        lstart[tid] = s[tid] - v;
        lcur[tid] = s[tid] - v;
        gbase[tid] = atomicAdd(&bcursor[tid], v);
    }
    __syncthreads();

    for (int j = tid; j < m; j += 512) {
        int sv = src[base + j], d = dst[base + j];
        int p = atomicAdd(&lcur[d >> 8], 1);
        lpairs[p] = make_int2(sv, d);
    }
    __syncthreads();
    for (int j = tid; j < m; j += 512) {
        int2 pr = lpairs[j];
        int b = pr.y >> 8;
        gpairs[gbase[b] + (j - lstart[b])] =
            ((unsigned int)pr.x << 8) | ((unsigned int)pr.y & 255u);
    }
}

// ---------------- pass 2: fused per-bucket build (packed input) ----------------
__global__ __launch_bounds__(256) void bucket_build_kernel(
        const unsigned int* __restrict__ gpairs, const int* __restrict__ bbase,
        int* __restrict__ off, int* __restrict__ ssorted,
        float* __restrict__ dsl, float* __restrict__ dnsl, int n, int e) {
    __shared__ int cnt[256];
    __shared__ int sc[256];
    int b = blockIdx.x, tid = threadIdx.x;
    int node0 = b << 8;
    int e0 = bbase[b], e1 = bbase[b + 1];

    cnt[tid] = 0;
    __syncthreads();
    for (int j = e0 + tid; j < e1; j += 256)
        atomicAdd(&cnt[gpairs[j] & 255u], 1);
    __syncthreads();

    int c = cnt[tid];
    sc[tid] = c; __syncthreads();
    for (int o = 1; o < 256; o <<= 1) {
        int t = (tid >= o) ? sc[tid - o] : 0;
        __syncthreads();
        sc[tid] += t;
        __syncthreads();
    }
    int excl = sc[tid] - c;

    int node = node0 + tid;
    if (node < n) {
        off[node] = e0 + excl;
        float cf = (float)c;
        dsl[node] = rsqrtf(cf + 1.0f);
        dnsl[node] = (c > 0) ? rsqrtf(cf) : 0.0f;
    }
    if (b == NBUK - 1 && tid == 0) off[n] = e;

    __syncthreads();
    cnt[tid] = e0 + excl;
    __syncthreads();
    for (int j = e0 + tid; j < e1; j += 256) {
        unsigned int pk = gpairs[j];
        int p = atomicAdd(&cnt[pk & 255u], 1);
        ssorted[p] = (int)(pk >> 8);
    }
}

// ---------------- pack all 4 W into MFMA fragment order + aux init block ----------------
__global__ void packW4_kernel(const float* __restrict__ W1, const float* __restrict__ W2,
                              const float* __restrict__ W3, const float* __restrict__ W4,
                              _Float16* __restrict__ Wt1, _Float16* __restrict__ Wt2,
                              _Float16* __restrict__ Wt3, _Float16* __restrict__ Wt4,
                              const float* __restrict__ b1, const float* __restrict__ b2,
                              float* __restrict__ b1p, float* __restrict__ b2p,
                              int* __restrict__ btotal, float* __restrict__ bnsum,
                              float* __restrict__ bnsq, __half* __restrict__ buf0zr) {
    if (blockIdx.x == 256) {
        // aux: pad biases, zero counters, zero gather pad-row
        int t = threadIdx.x;
        if (t < 128) {
            b1p[t] = (t < DIM) ? b1[t] : 0.f;
            b2p[t] = (t < DIM) ? b2[t] : 0.f;
            bnsum[t] = 0.f;
            bnsq[t] = 0.f;
        }
        for (int i = t; i < NBUK; i += 256) btotal[i] = 0;
        if (t < 64) ((unsigned int*)buf0zr)[t] = 0u;   // row n of buf0 = zeros (256 B)
        return;
    }
    int which = blockIdx.x >> 6;          // 64 blocks per weight
    int idx = (blockIdx.x & 63) * 256 + threadIdx.x;
    const float* W = (which == 0) ? W1 : (which == 1) ? W2 : (which == 2) ? W3 : W4;
    _Float16* Wt  = (which == 0) ? Wt1 : (which == 1) ? Wt2 : (which == 2) ? Wt3 : Wt4;
    int K = (which == 0) ? 128 : DIM;
    int j = idx & 7;
    int l = (idx >> 3) & 63;
    int c = idx >> 9;
    int t = c >> 2, k0 = c & 3;
    int nn = t * 16 + (l & 15);
    int k = k0 * 32 + (l >> 4) * 8 + j;
    float v = (k < K && nn < DIM) ? W[k * DIM + nn] : 0.f;
    Wt[idx] = (_Float16)v;
}

// ---------------- propagation (self-loop) : out = relu(dinv*sum + bias) ----------------
// All gather steps run the 16-wide ILP-4 path; invalid slots read the zero row (ZR=n).
__global__ __launch_bounds__(256) void prop_kernel(
        const __half* __restrict__ pre, const int* __restrict__ ssorted,
        const int* __restrict__ off, const float* __restrict__ dinv,
        const float* __restrict__ bias, __half* __restrict__ outH, int n) {
    int wave = (blockIdx.x * blockDim.x + threadIdx.x) >> 6;
    int lane = threadIdx.x & 63;
    if (wave >= n) return;
    int e0 = off[wave], e1 = off[wave + 1];
    int deg = e1 - e0;
    int g = lane >> 4;
    int q = lane & 15;
    const int ZR = n;

    float acc[8];
#pragma unroll
    for (int i = 0; i < 8; i++) acc[i] = 0.f;

    auto addu = [&](uint4 u) {
        float2 f;
        f = __half22float2(*(__half2*)&u.x); acc[0] += f.x; acc[1] += f.y;
        f = __half22float2(*(__half2*)&u.y); acc[2] += f.x; acc[3] += f.y;
        f = __half22float2(*(__half2*)&u.z); acc[4] += f.x; acc[5] += f.y;
        f = __half22float2(*(__half2*)&u.w); acc[6] += f.x; acc[7] += f.y;
    };
    auto rowptr = [&](int s) -> const uint4* {
        return (const uint4*)&pre[(long)s * DP + q * 8];
    };

    for (int base = 0; base < deg; base += 64) {
        int m = deg - base; if (m > 64) m = 64;
        int sidx = (lane < m) ? ssorted[e0 + base + lane] : ZR;
        for (int j = 0; j < m; j += 16) {
            int s0 = __shfl(sidx, j + g);
            int s1 = __shfl(sidx, j + 4 + g);
            int s2 = __shfl(sidx, j + 8 + g);
            int s3 = __shfl(sidx, j + 12 + g);
            uint4 u0 = *rowptr(s0);
            uint4 u1 = *rowptr(s1);
            uint4 u2 = *rowptr(s2);
            uint4 u3 = *rowptr(s3);
            addu(u0); addu(u1); addu(u2); addu(u3);
        }
    }

#pragma unroll
    for (int i = 0; i < 8; i++) {
        acc[i] += __shfl_xor(acc[i], 16);
        acc[i] += __shfl_xor(acc[i], 32);
    }

    if (g == 0) {
        float dn = dinv[wave];
        addu(*rowptr(wave));                // self-loop (pre already dsl-scaled)
        float4 b0 = *(const float4*)&bias[q * 8];
        float4 b1v = *(const float4*)&bias[q * 8 + 4];
        float o[8];
        o[0] = fmaxf(dn * acc[0] + b0.x, 0.f);
        o[1] = fmaxf(dn * acc[1] + b0.y, 0.f);
        o[2] = fmaxf(dn * acc[2] + b0.z, 0.f);
        o[3] = fmaxf(dn * acc[3] + b0.w, 0.f);
        o[4] = fmaxf(dn * acc[4] + b1v.x, 0.f);
        o[5] = fmaxf(dn * acc[5] + b1v.y, 0.f);
        o[6] = fmaxf(dn * acc[6] + b1v.z, 0.f);
        o[7] = fmaxf(dn * acc[7] + b1v.w, 0.f);
        __half2 p0 = __floats2half2_rn(o[0], o[1]);
        __half2 p1 = __floats2half2_rn(o[2], o[3]);
        __half2 p2 = __floats2half2_rn(o[4], o[5]);
        __half2 p3 = __floats2half2_rn(o[6], o[7]);
        uint4 u;
        u.x = *(unsigned int*)&p0;
        u.y = *(unsigned int*)&p1;
        u.z = *(unsigned int*)&p2;
        u.w = *(unsigned int*)&p3;
        *(uint4*)&outH[(long)wave * DP + q * 8] = u;
    }
}

// ---------------- ARMA prop: out = relu(dinv*sum + R), no self-loop ----------------
__global__ __launch_bounds__(256) void prop_arma_kernel(
        const __half* __restrict__ pre, const int* __restrict__ ssorted,
        const int* __restrict__ off, const float* __restrict__ dinv,
        const __half* __restrict__ R, __half* __restrict__ outH, int n) {
    int wave = (blockIdx.x * blockDim.x + threadIdx.x) >> 6;
    int lane = threadIdx.x & 63;
    if (wave >= n) return;
    int e0 = off[wave], e1 = off[wave + 1];
    int deg = e1 - e0;
    int g = lane >> 4;
    int q = lane & 15;
    const int ZR = n;

    float acc[8];
#pragma unroll
    for (int i = 0; i < 8; i++) acc[i] = 0.f;

    auto addu = [&](uint4 u) {
        float2 f;
        f = __half22float2(*(__half2*)&u.x); acc[0] += f.x; acc[1] += f.y;
        f = __half22float2(*(__half2*)&u.y); acc[2] += f.x; acc[3] += f.y;
        f = __half22float2(*(__half2*)&u.z); acc[4] += f.x; acc[5] += f.y;
        f = __half22float2(*(__half2*)&u.w); acc[6] += f.x; acc[7] += f.y;
    };
    auto rowptr = [&](int s) -> const uint4* {
        return (const uint4*)&pre[(long)s * DP + q * 8];
    };

    for (int base = 0; base < deg; base += 64) {
        int m = deg - base; if (m > 64) m = 64;
        int sidx = (lane < m) ? ssorted[e0 + base + lane] : ZR;
        for (int j = 0; j < m; j += 16) {
            int s0 = __shfl(sidx, j + g);
            int s1 = __shfl(sidx, j + 4 + g);
            int s2 = __shfl(sidx, j + 8 + g);
            int s3 = __shfl(sidx, j + 12 + g);
            uint4 u0 = *rowptr(s0);
            uint4 u1 = *rowptr(s1);
            uint4 u2 = *rowptr(s2);
            uint4 u3 = *rowptr(s3);
            addu(u0); addu(u1); addu(u2); addu(u3);
        }
    }

#pragma unroll
    for (int i = 0; i < 8; i++) {
        acc[i] += __shfl_xor(acc[i], 16);
        acc[i] += __shfl_xor(acc[i], 32);
    }

    if (g == 0) {
        float dn = dinv[wave];
        uint4 r4 = *(const uint4*)&R[(long)wave * DP + q * 8];
        float rr[8];
        float2 f;
        f = __half22float2(*(__half2*)&r4.x); rr[0] = f.x; rr[1] = f.y;
        f = __half22float2(*(__half2*)&r4.y); rr[2] = f.x; rr[3] = f.y;
        f = __half22float2(*(__half2*)&r4.z); rr[4] = f.x; rr[5] = f.y;
        f = __half22float2(*(__half2*)&r4.w); rr[6] = f.x; rr[7] = f.y;
        float o[8];
#pragma unroll
        for (int i = 0; i < 8; i++) o[i] = fmaxf(dn * acc[i] + rr[i], 0.f);
        __half2 p0 = __floats2half2_rn(o[0], o[1]);
        __half2 p1 = __floats2half2_rn(o[2], o[3]);
        __half2 p2 = __floats2half2_rn(o[4], o[5]);
        __half2 p3 = __floats2half2_rn(o[6], o[7]);
        uint4 u;
        u.x = *(unsigned int*)&p0;
        u.y = *(unsigned int*)&p1;
        u.z = *(unsigned int*)&p2;
        u.w = *(unsigned int*)&p3;
        *(uint4*)&outH[(long)wave * DP + q * 8] = u;
    }
}

// ---------------- MFMA matmul, fp32 A (x input), 128 rows/block: C = (A@W)*rowscale -> fp16 DP ----------------
__global__ __launch_bounds__(256) void matmul_a32_kernel(
        const float* __restrict__ A, const _Float16* __restrict__ WtF,
        const float* __restrict__ rowscale, __half* __restrict__ Ch, int M) {
    __shared__ char smraw[64 * 132 * 4];
    _Float16* Bs = (_Float16*)smraw;
    float* Ct = (float*)smraw;
    int tid = threadIdx.x;
    int wave = tid >> 6;
    int lane = tid & 63;
    int m16 = lane & 15;
    int quad = lane >> 4;
    long row0blk = (long)blockIdx.x * 128;

    {
        const uint4* s = (const uint4*)WtF;
        uint4* d = (uint4*)Bs;
        for (int i = tid; i < 2048; i += 256) d[i] = s[i];
    }

    half8 af[2][4];
#pragma unroll
    for (int t = 0; t < 2; t++) {
        long ar = row0blk + t * 64 + wave * 16 + m16; if (ar >= M) ar = M - 1;
        const float* Ap = &A[ar * DP + quad * 8];
#pragma unroll
        for (int k0 = 0; k0 < 4; k0++) {
            float4 v0 = *(const float4*)(Ap + k0 * 32);
            float4 v1 = *(const float4*)(Ap + k0 * 32 + 4);
            half8 o;
            o[0] = (_Float16)v0.x; o[1] = (_Float16)v0.y;
            o[2] = (_Float16)v0.z; o[3] = (_Float16)v0.w;
            o[4] = (_Float16)v1.x; o[5] = (_Float16)v1.y;
            o[6] = (_Float16)v1.z; o[7] = (_Float16)v1.w;
            af[t][k0] = o;
        }
    }
    __syncthreads();

    floatx4 acc[2][8];
#pragma unroll
    for (int t = 0; t < 2; t++)
#pragma unroll
        for (int a = 0; a < 8; a++) acc[t][a] = (floatx4){0.f, 0.f, 0.f, 0.f};

#pragma unroll
    for (int c = 0; c < 32; c++) {
        half8 bf = *(const half8*)&Bs[(c * 64 + lane) * 8];
        acc[0][c >> 2] = __builtin_amdgcn_mfma_f32_16x16x32_f16(af[0][c & 3], bf, acc[0][c >> 2], 0, 0, 0);
        acc[1][c >> 2] = __builtin_amdgcn_mfma_f32_16x16x32_f16(af[1][c & 3], bf, acc[1][c >> 2], 0, 0, 0);
    }

    int lrow0 = wave * 16 + quad * 4;
#pragma unroll
    for (int t = 0; t < 2; t++) {
        __syncthreads();
#pragma unroll
        for (int a = 0; a < 8; a++)
#pragma unroll
            for (int r = 0; r < 4; r++)
                Ct[(lrow0 + r) * 132 + a * 16 + m16] = acc[t][a][r];
        __syncthreads();
        for (int idx = tid; idx < 64 * 32; idx += 256) {
            int lr = idx >> 5, c4 = idx & 31;
            long grow = row0blk + t * 64 + lr;
            if (grow >= M) continue;
            int col = c4 * 4;
            float4 v = *(const float4*)&Ct[lr * 132 + col];
            float rs = rowscale[grow];
            v.x *= rs; v.y *= rs; v.z *= rs; v.w *= rs;
            __half2 p01 = __floats2half2_rn(v.x, v.y);
            __half2 p23 = __floats2half2_rn(v.z, v.w);
            uint2 u;
            u.x = *(unsigned int*)&p01;
            u.y = *(unsigned int*)&p23;
            *(uint2*)&Ch[grow * DP + col] = u;
        }
    }
}

// ---------------- MFMA matmul, fp16 A (DP stride), 128 rows/block: C = (A@W)*rowscale -> fp16 DP ----------------
__global__ __launch_bounds__(256) void matmul_a16_kernel(
        const __half* __restrict__ A, const _Float16* __restrict__ WtF,
        const float* __restrict__ rowscale, __half* __restrict__ Ch, int M) {
    __shared__ char smraw[64 * 132 * 4];
    _Float16* Bs = (_Float16*)smraw;
    float* Ct = (float*)smraw;
    int tid = threadIdx.x;
    int wave = tid >> 6;
    int lane = tid & 63;
    int m16 = lane & 15;
    int quad = lane >> 4;
    long row0blk = (long)blockIdx.x * 128;

    {
        const uint4* s = (const uint4*)WtF;
        uint4* d = (uint4*)Bs;
        for (int i = tid; i < 2048; i += 256) d[i] = s[i];
    }

    half8 af[2][4];
#pragma unroll
    for (int t = 0; t < 2; t++) {
        long ar = row0blk + t * 64 + wave * 16 + m16; if (ar >= M) ar = M - 1;
        const _Float16* Ap = (const _Float16*)&A[ar * DP + quad * 8];
#pragma unroll
        for (int k0 = 0; k0 < 4; k0++)
            af[t][k0] = *(const half8*)(Ap + k0 * 32);
    }
    __syncthreads();

    floatx4 acc[2][8];
#pragma unroll
    for (int t = 0; t < 2; t++)
#pragma unroll
        for (int a = 0; a < 8; a++) acc[t][a] = (floatx4){0.f, 0.f, 0.f, 0.f};

#pragma unroll
    for (int c = 0; c < 32; c++) {
        half8 bf = *(const half8*)&Bs[(c * 64 + lane) * 8];
        acc[0][c >> 2] = __builtin_amdgcn_mfma_f32_16x16x32_f16(af[0][c & 3], bf, acc[0][c >> 2], 0, 0, 0);
        acc[1][c >> 2] = __builtin_amdgcn_mfma_f32_16x16x32_f16(af[1][c & 3], bf, acc[1][c >> 2], 0, 0, 0);
    }

    int lrow0 = wave * 16 + quad * 4;
#pragma unroll
    for (int t = 0; t < 2; t++) {
        __syncthreads();
#pragma unroll
        for (int a = 0; a < 8; a++)
#pragma unroll
            for (int r = 0; r < 4; r++)
                Ct[(lrow0 + r) * 132 + a * 16 + m16] = acc[t][a][r];
        __syncthreads();
        for (int idx = tid; idx < 64 * 32; idx += 256) {
            int lr = idx >> 5, c4 = idx & 31;
            long grow = row0blk + t * 64 + lr;
            if (grow >= M) continue;
            int col = c4 * 4;
            float4 v = *(const float4*)&Ct[lr * 132 + col];
            float rs = rowscale[grow];
            v.x *= rs; v.y *= rs; v.z *= rs; v.w *= rs;
            __half2 p01 = __floats2half2_rn(v.x, v.y);
            __half2 p23 = __floats2half2_rn(v.z, v.w);
            uint2 u;
            u.x = *(unsigned int*)&p01;
            u.y = *(unsigned int*)&p23;
            *(uint2*)&Ch[grow * DP + col] = u;
        }
    }
}

// ---------------- dual MFMA matmul, BN params computed in-block from stats:
//                  P1 = BN(A)@W3*rowscale ; R = BN(A)@W4 + ba ----------------
__global__ __launch_bounds__(256) void matmul_dual_kernel(
        const __half* __restrict__ A, const _Float16* __restrict__ WtF3,
        const _Float16* __restrict__ WtF4, const float* __restrict__ ba,
        const float* __restrict__ rowscale,
        const float* __restrict__ bnsum, const float* __restrict__ bnsq,
        const float* __restrict__ gamma, const float* __restrict__ beta,
        __half* __restrict__ Ch1, __half* __restrict__ ChR, int M, int Kout) {
    __shared__ char smraw[64 * 132 * 4];
    __shared__ float bnS[DP], bnH[DP];
    _Float16* Bs = (_Float16*)smraw;
    float* Ct = (float*)smraw;
    int tid = threadIdx.x;
    int wave = tid >> 6;
    int lane = tid & 63;
    int m16 = lane & 15;
    int quad = lane >> 4;
    long row0blk = (long)blockIdx.x * 64;
    long row0 = row0blk + wave * 16;

    // BN scale/shift from stats (identical fp32 math to former bn_prep_kernel)
    if (tid < DP) {
        float sc = 0.f, sh = 0.f;
        if (tid < DIM) {
            float inv_n = 1.0f / (float)M;
            float mu = bnsum[tid] * inv_n;
            float var = bnsq[tid] * inv_n - mu * mu;
            float rs = rsqrtf(var + EPSBN);
            sc = rs * gamma[tid];
            sh = beta[tid] - mu * sc;
        }
        bnS[tid] = sc;
        bnH[tid] = sh;
    }
    __syncthreads();

    half8 af[4];
    {
        long ar = row0 + m16; if (ar >= M) ar = M - 1;
        const _Float16* Ap = (const _Float16*)&A[ar * DP + quad * 8];
#pragma unroll
        for (int k0 = 0; k0 < 4; k0++) {
            half8 h = *(const half8*)(Ap + k0 * 32);
            int c0 = quad * 8 + k0 * 32;
            half8 o;
#pragma unroll
            for (int jj = 0; jj < 8; jj++)
                o[jj] = (_Float16)((float)h[jj] * bnS[c0 + jj] + bnH[c0 + jj]);
            af[k0] = o;
        }
    }

    floatx4 acc3[8], acc4[8];
#pragma unroll
    for (int t = 0; t < 8; t++) {
        acc3[t] = (floatx4){0.f, 0.f, 0.f, 0.f};
        acc4[t] = (floatx4){0.f, 0.f, 0.f, 0.f};
    }

    // --- W3 pass ---
    {
        const uint4* s = (const uint4*)WtF3;
        uint4* d = (uint4*)Bs;
        for (int i = tid; i < 2048; i += 256) d[i] = s[i];
    }
    __syncthreads();
#pragma unroll
    for (int c = 0; c < 32; c++) {
        half8 bf = *(const half8*)&Bs[(c * 64 + lane) * 8];
        acc3[c >> 2] = __builtin_amdgcn_mfma_f32_16x16x32_f16(af[c & 3], bf, acc3[c >> 2], 0, 0, 0);
    }
    __syncthreads();

    // --- W4 pass ---
    {
        const uint4* s = (const uint4*)WtF4;
        uint4* d = (uint4*)Bs;
        for (int i = tid; i < 2048; i += 256) d[i] = s[i];
    }
    __syncthreads();
#pragma unroll
    for (int c = 0; c < 32; c++) {
        half8 bf = *(const half8*)&Bs[(c * 64 + lane) * 8];
        acc4[c >> 2] = __builtin_amdgcn_mfma_f32_16x16x32_f16(af[c & 3], bf, acc4[c >> 2], 0, 0, 0);
    }
    __syncthreads();

    int lrow0 = wave * 16 + quad * 4;

    // --- P1 epilogue: rowscale only ---
#pragma unroll
    for (int t = 0; t < 8; t++)
#pragma unroll
        for (int r = 0; r < 4; r++)
            Ct[(lrow0 + r) * 132 + t * 16 + m16] = acc3[t][r];
    __syncthreads();
    for (int idx = tid; idx < 64 * 32; idx += 256) {
        int lr = idx >> 5, c4 = idx & 31;
        long grow = row0blk + lr;
        if (grow >= M) continue;
        int col = c4 * 4;
        float4 v = *(const float4*)&Ct[lr * 132 + col];
        float rs = rowscale[grow];
        v.x *= rs; v.y *= rs; v.z *= rs; v.w *= rs;
        __half2 p01 = __floats2half2_rn(v.x, v.y);
        __half2 p23 = __floats2half2_rn(v.z, v.w);
        uint2 u;
        u.x = *(unsigned int*)&p01;
        u.y = *(unsigned int*)&p23;
        *(uint2*)&Ch1[grow * DP + col] = u;
    }
    __syncthreads();

    // --- R epilogue: +ba ---
#pragma unroll
    for (int t = 0; t < 8; t++)
#pragma unroll
        for (int r = 0; r < 4; r++)
            Ct[(lrow0 + r) * 132 + t * 16 + m16] = acc4[t][r];
    __syncthreads();
    for (int idx = tid; idx < 64 * 32; idx += 256) {
        int lr = idx >> 5, c4 = idx & 31;
        long grow = row0blk + lr;
        if (grow >= M) continue;
        int col = c4 * 4;
        float4 v = *(const float4*)&Ct[lr * 132 + col];
        if (col + 4 <= Kout) {
            float4 bb = *(const float4*)&ba[col];
            v.x += bb.x; v.y += bb.y; v.z += bb.z; v.w += bb.w;
        }
        __half2 p01 = __floats2half2_rn(v.x, v.y);
        __half2 p23 = __floats2half2_rn(v.z, v.w);
        uint2 u;
        u.x = *(unsigned int*)&p01;
        u.y = *(unsigned int*)&p23;
        *(uint2*)&ChR[grow * DP + col] = u;
    }
}

// ---------------- BN stats over h2 (DP stride) ----------------
__global__ __launch_bounds__(512) void bnstats_kernel(const __half* __restrict__ h,
                                                      float* __restrict__ bnsum,
                                                      float* __restrict__ bnsq, int n) {
    __shared__ float2 sred[512], qred[512];
    int tid = threadIdx.x;
    int col2 = tid & 63;
    int rgrp = tid >> 6;                      // 8 row groups
    float2 s = make_float2(0.f, 0.f), qv = make_float2(0.f, 0.f);
    if (col2 < 52) {
        for (int r = blockIdx.x * 8 + rgrp; r < n; r += gridDim.x * 8) {
            __half2 hv = *(const __half2*)&h[(long)r * DP + col2 * 2];
            float2 f = __half22float2(hv);
            s.x += f.x; s.y += f.y;
            qv.x += f.x * f.x; qv.y += f.y * f.y;
        }
    }
    sred[tid] = s; qred[tid] = qv;
    __syncthreads();
    if (tid < 52) {
        float2 ts = make_float2(0.f, 0.f), tq = make_float2(0.f, 0.f);
#pragma unroll
        for (int gg = 0; gg < 8; gg++) {
            float2 v = sred[gg * 64 + tid]; ts.x += v.x; ts.y += v.y;
            v = qred[gg * 64 + tid]; tq.x += v.x; tq.y += v.y;
        }
        atomicAdd(&bnsum[tid * 2], ts.x);
        atomicAdd(&bnsum[tid * 2 + 1], ts.y);
        atomicAdd(&bnsq[tid * 2], tq.x);
        atomicAdd(&bnsq[tid * 2 + 1], tq.y);
    }
}

// ---------------- fused global add pool + MLP head ----------------
__global__ __launch_bounds__(512) void pmlp_kernel(
        const __half* __restrict__ a, const int* __restrict__ gstart,
        const float* __restrict__ Wf1, const float* __restrict__ bf1,
        const float* __restrict__ Wf2, const float* __restrict__ bf2,
        const float* __restrict__ Wf3, const float* __restrict__ bf3,
        const float* __restrict__ Wf4, const float* __restrict__ bf4,
        float* __restrict__ out) {
    __shared__ float2 red[512];
    __shared__ float gsum[128], a1[200], a2[300], a3[200], red1[512];
    int b = blockIdx.x, tid = threadIdx.x;

    // ---- pool phase ----
    {
        int col2 = tid & 63;
        int rgrp = tid >> 6;
        int lo = gstart[b], hi = gstart[b + 1];
        float2 s = make_float2(0.f, 0.f);
        for (int r = lo + rgrp; r < hi; r += 8) {
            __half2 h = *(const __half2*)&a[(long)r * DP + col2 * 2];
            float2 f = __half22float2(h);
            s.x += f.x; s.y += f.y;
        }
        red[tid] = s;
        __syncthreads();
        if (tid < 64) {
            float2 t = make_float2(0.f, 0.f);
#pragma unroll
            for (int gg = 0; gg < 8; gg++) {
                float2 v = red[gg * 64 + tid];
                t.x += v.x; t.y += v.y;
            }
            gsum[tid * 2] = t.x;
            gsum[tid * 2 + 1] = t.y;
        }
        __syncthreads();
    }

    // ---- MLP phase ----
    for (int c = tid; c < 200; c += 512) {
        float s = bf1[c];
        for (int k = 0; k < 100; k++) s += gsum[k] * Wf1[k * 200 + c];
        a1[c] = fmaxf(s, 0.f);
    }
    __syncthreads();
    for (int c = tid; c < 300; c += 512) {
        float s = bf2[c];
        for (int k = 0; k < 200; k++) s += a1[k] * Wf2[k * 300 + c];
        a2[c] = fmaxf(s, 0.f);
    }
    __syncthreads();
    for (int c = tid; c < 200; c += 512) {
        float s = bf3[c];
        for (int k = 0; k < 300; k++) s += a2[k] * Wf3[k * 200 + c];
        a3[c] = fmaxf(s, 0.f);
    }
    __syncthreads();
    red1[tid] = (tid < 200) ? a3[tid] * Wf4[tid] : 0.f;
    __syncthreads();
    for (int o = 256; o > 0; o >>= 1) {
        if (tid < o) red1[tid] += red1[tid + o];
        __syncthreads();
    }
    if (tid == 0) out[b] = red1[0] + bf4[0];
}

extern "C" void kernel_launch(void* const* d_in, const int* in_sizes, int n_in,
                              void* d_out, int out_size, void* d_ws, size_t ws_size,
                              hipStream_t stream) {
    const float* x      = (const float*)d_in[0];
    const int*   src    = (const int*)d_in[1];
    const int*   dst    = (const int*)d_in[2];
    const int*   batch  = (const int*)d_in[3];
    const float* W1     = (const float*)d_in[4];
    const float* b1     = (const float*)d_in[5];
    const float* W2     = (const float*)d_in[6];
    const float* b2     = (const float*)d_in[7];
    const float* gamma  = (const float*)d_in[8];
    const float* beta   = (const float*)d_in[9];
    const float* Wa_init= (const float*)d_in[10];
    const float* Wa_root= (const float*)d_in[11];
    const float* ba     = (const float*)d_in[12];
    const float* Wf1    = (const float*)d_in[13];
    const float* bf1    = (const float*)d_in[14];
    const float* Wf2    = (const float*)d_in[15];
    const float* bf2    = (const float*)d_in[16];
    const float* Wf3    = (const float*)d_in[17];
    const float* bf3    = (const float*)d_in[18];
    const float* Wf4    = (const float*)d_in[19];
    const float* bf4    = (const float*)d_in[20];
    float* out = (float*)d_out;

    const int n = NNODES;
    const int e = NEDGES;

    char* ws = (char*)d_ws;
    auto carve = [&](size_t bytes) -> void* {
        void* p = (void*)ws;
        ws += (bytes + 255) & ~(size_t)255;
        return p;
    };
    __half* buf0    = (__half*)carve((size_t)(n + 1) * DP * 2);  // Y1/Y2/P1 (+zero pad row n)
    __half* buf1    = (__half*)carve((size_t)n * DP * 2);        // H1 / H2
    __half* bufR    = (__half*)carve((size_t)n * DP * 2);        // R
    __half* bufC    = (__half*)carve((size_t)n * DP * 2);        // ARMA out
    _Float16* Wt1   = (_Float16*)carve((size_t)DP * DP * 2);
    _Float16* Wt2   = (_Float16*)carve((size_t)DP * DP * 2);
    _Float16* Wt3   = (_Float16*)carve((size_t)DP * DP * 2);
    _Float16* Wt4   = (_Float16*)carve((size_t)DP * DP * 2);
    int*    off     = (int*)carve((size_t)(n + 1) * 4);
    int*    btotal  = (int*)carve((size_t)NBUK * 4);
    int*    bbase   = (int*)carve((size_t)(NBUK + 1) * 4);
    int*    bcursor = (int*)carve((size_t)NBUK * 4);
    int*    ssorted = (int*)carve((size_t)e * 4);
    unsigned int* gpairs = (unsigned int*)carve((size_t)e * 4);
    float*  dinv_sl = (float*)carve((size_t)n * 4);
    float*  dinv_nsl= (float*)carve((size_t)n * 4);
    float*  bnsum   = (float*)carve(DP * 4);
    float*  bnsq    = (float*)carve(DP * 4);
    float*  b1p     = (float*)carve(DP * 4);
    float*  b2p     = (float*)carve(DP * 4);
    int*    gstart  = (int*)carve((size_t)(NGRAPH + 1) * 4);

    const int nchunk = (e + BINCH - 1) / BINCH;

    // ---- pack weights + aux init (biases, counters, zero-row) ----
    packW4_kernel<<<257, 256, 0, stream>>>(W1, W2, Wa_init, Wa_root, Wt1, Wt2, Wt3, Wt4,
                                           b1, b2, b1p, b2p, btotal, bnsum, bnsq,
                                           buf0 + (size_t)n * DP);

    // ---- build CSR by dst ----
    bin_count_kernel<<<nchunk, 512, 0, stream>>>(dst, btotal, e);
    bucket_scan_kernel<<<1, 512, 0, stream>>>(btotal, bbase, bcursor, e, batch, gstart, n);
    bin_kernel<<<nchunk, 512, 0, stream>>>(src, dst, bcursor, gpairs, e);
    bucket_build_kernel<<<NBUK, 256, 0, stream>>>(gpairs, bbase, off, ssorted, dinv_sl, dinv_nsl, n, e);

    const int prop_blocks = (n + 3) / 4;
    const int mm_blocks128 = (n + 127) / 128;
    const int mm_blocks64 = (n + 63) / 64;

    // ---- SGConv 1 (matmul first: prop(x)@W1 == prop(x@W1)) ----
    matmul_a32_kernel<<<mm_blocks128, 256, 0, stream>>>(x, Wt1, dinv_sl, buf0, n);
    prop_kernel<<<prop_blocks, 256, 0, stream>>>(buf0, ssorted, off, dinv_sl, b1p, buf1, n);

    // ---- SGConv 2 ----
    matmul_a16_kernel<<<mm_blocks128, 256, 0, stream>>>(buf1, Wt2, dinv_sl, buf0, n);
    prop_kernel<<<prop_blocks, 256, 0, stream>>>(buf0, ssorted, off, dinv_sl, b2p, buf1, n);

    // ---- BatchNorm stats (params computed inside dual matmul) ----
    bnstats_kernel<<<512, 512, 0, stream>>>(buf1, bnsum, bnsq, n);

    // ---- ARMAConv: dual matmul with fused BN, then prop with fused add+relu ----
    matmul_dual_kernel<<<mm_blocks64, 256, 0, stream>>>(buf1, Wt3, Wt4, ba, dinv_nsl,
                                                        bnsum, bnsq, gamma, beta, buf0, bufR, n, DIM);
    prop_arma_kernel<<<prop_blocks, 256, 0, stream>>>(buf0, ssorted, off, dinv_nsl, bufR, bufC, n);

    // ---- fused global add pool + MLP head ----
    pmlp_kernel<<<NGRAPH, 512, 0, stream>>>(bufC, gstart, Wf1, bf1, Wf2, bf2, Wf3, bf3, Wf4, bf4, out);
}